// Round 3
// baseline (653.330 us; speedup 1.0000x reference)
//
#include <hip/hip_runtime.h>
#include <math.h>

// x:[2,256,256,512] f32 -> out:[2,256,128,256] f32
// Planes p = 2m (Re), 2m+1 (Im), m=0..127.
// Spectral legs fused: g[p] = X[p] * Q[m]^T, Q[m] = PT[m] * WM[m] (precomputed).

#define ROWS_HI 131072   // B*C*H_HI
#define ROWS_LO 65536    // B*C*H_LO

// ws byte offsets (no aliasing; ws >= 1 GiB per harness fill)
#define B_FT    0LL            // F_T  bf16 [256 p][512 w]          256 KB
#define B_FIT   262144LL       // Fi_T bf16 [256 w'][256 p]         128 KB
#define B_WM    393216LL       // wmat bf16 [128 m][128 l][256 k]   8 MB
#define B_PCT   8781824LL      // pctT bf16 [128 m][128 kp][128 l]  4 MB
#define B_WB    12976128LL     // conv_w bf16 [256 o][256 c]        128 KB
#define B_STATS 13107200LL     // 128 floats
#define B_WMT   13107712LL     // wmatT bf16 [128 m][256 k][128 l]  8 MB
#define B_QM    21496320LL     // Q bf16 [128 m][128 kp][256 k]     8 MB
#define B_XBF   29884928LL     // Xbf bf16 [256 p][131072 r]        64 MB
#define B_GB    96993792LL     // gb  bf16 [256 p][65536 r_lo]      32 MB
#define B_GTB   130548224LL    // gTb bf16 [65536 r_lo][256 p]      32 MB
#define B_Y     164102656LL    // y   f32  [65536 r_lo][256 w']     64 MB
#define B_YT    231211520LL    // yT  bf16 [b][32768 s][256 c]      32 MB
// total ~265 MB

typedef __attribute__((ext_vector_type(8))) short bf16x8;
typedef __attribute__((ext_vector_type(8))) unsigned short ushort8;
typedef __attribute__((ext_vector_type(4))) unsigned short ushort4v;
typedef __attribute__((ext_vector_type(4))) float f32x4;

__device__ inline unsigned short f2bf(float f){
  unsigned int u = __float_as_uint(f);
  unsigned int r = u + 0x7FFFu + ((u >> 16) & 1u);
  return (unsigned short)(r >> 16);
}

// async global->LDS, 16B per lane; LDS dest is wave-uniform base + lane*16.
__device__ inline void gl_lds16(const unsigned short* g, unsigned short* l){
  __builtin_amdgcn_global_load_lds(
      (const __attribute__((address_space(1))) unsigned int*)g,
      (__attribute__((address_space(3))) unsigned int*)l, 16, 0, 0);
}

// ---------------- tables: DFT/iDFT twiddles (bf16) + zero stats ---------------
__global__ __launch_bounds__(256) void k_tables(unsigned char* __restrict__ ws){
  unsigned short* FT  = (unsigned short*)(ws + B_FT);
  unsigned short* FIT = (unsigned short*)(ws + B_FIT);
  float* stats = (float*)(ws + B_STATS);
  int idx = blockIdx.x*256 + threadIdx.x;
  if (idx < 131072){            // F_T[p][w]
    int p = idx >> 9, w = idx & 511, m = p >> 1;
    int pr = (m*w) & 511;
    float ang = (float)pr * (float)(2.0*M_PI/512.0);
    float s, c; sincosf(ang, &s, &c);
    const float S = (float)(2.0*M_PI/512.0);
    FT[idx] = f2bf((p & 1) ? (-S*s) : (S*c));
  }
  int i2 = idx - 131072;
  if (i2 >= 0 && i2 < 65536){   // Fi_T[w'][p]
    int w = i2 >> 8, p = i2 & 255, m = p >> 1;
    float eps = (m == 0) ? 1.f : 2.f;
    int pr = (m*w) & 255;
    float ang = (float)pr * (float)(2.0*M_PI/256.0);
    float s, c; sincosf(ang, &s, &c);
    FIT[i2] = f2bf((p & 1) ? (-eps*s) : (eps*c));
  }
  int i3 = idx - (131072 + 65536);
  if (i3 >= 0 && i3 < 128) stats[i3] = 0.f;
}

// ------- prep: wmat->bf16 (+transposed copy), pct->bf16 T, conv_w->bf16 ------
__global__ __launch_bounds__(256) void k_prep(const float* __restrict__ wmat,
                                              const float* __restrict__ pct,
                                              const float* __restrict__ Wc,
                                              unsigned char* __restrict__ ws){
  unsigned short* WM  = (unsigned short*)(ws + B_WM);
  unsigned short* PT  = (unsigned short*)(ws + B_PCT);
  unsigned short* WB  = (unsigned short*)(ws + B_WB);
  unsigned short* WMT = (unsigned short*)(ws + B_WMT);
  int idx = blockIdx.x*256 + threadIdx.x;
  if (idx < 4194304){
    WM[idx] = f2bf(wmat[idx]);            // [m][l][k] direct, m<128
  } else if (idx < 6291456){
    int j = idx - 4194304;                // pctT[m][kp][l] = pct[m][l][kp]
    int m = j >> 14, kp = (j >> 7) & 127, l = j & 127;
    PT[j] = f2bf(pct[m*16384 + l*128 + kp]);
  } else if (idx < 6356992){
    int j = idx - 6291456;
    WB[j] = f2bf(Wc[j]);                  // [o][c]
  } else if (idx < 10551296){
    int j = idx - 6356992;                // WMT[m][k][l] = wmat[m][l][k]
    int m = j >> 15, k = (j >> 7) & 255, l = j & 127;
    WMT[j] = f2bf(wmat[m*32768 + l*256 + k]);
  }
}

// ---------------- MFMA GEMM core (m97 structure) ------------------------------
// C[M][N] = A[M][K] * B_T[N][K]^T ; BM=BN=128, BK=32, 256 thr, 2x2 waves,
// each wave 64x64 (4x4 16x16x32 bf16 MFMA frags, acc=64 VGPR).
// Staging via global_load_lds (16B/lane) into LINEAR LDS [128][32].
// AMODE 0: A fp32, reg-staged + quantize to bf16 (DFT only)
// AMODE 1: A bf16 via global_load_lds
// CMODE 0: row-major fp32 store (+optional bias[row])
// CMODE 1: transposed bf16 store C_T[col][row]
// CMODE 2: row-major bf16 store
// SKIP 2: k-loop starts at (m>>5)  (Q-gemm: contraction over l >= m)
// MZSH: m = blockIdx.z >> MZSH
template<int AMODE, int CMODE, bool BIAS, int SKIP, int MZSH, int WPE>
__global__ __launch_bounds__(256, WPE) void k_gemm(
    const float* __restrict__ Af,
    const unsigned short* __restrict__ Abf,
    const unsigned short* __restrict__ Bt,
    float* __restrict__ Cf,
    unsigned short* __restrict__ Cbf,
    const float* __restrict__ bias,
    int ldA, int ldB, int ldC, int ksteps,
    long long sA, long long sB, int bzsh, long long sC)
{
  __shared__ __align__(16) unsigned short As[128][32];
  __shared__ __align__(16) unsigned short Bs[128][32];
  const int tid = threadIdx.x;
  const int z = blockIdx.z;
  const int m = z >> MZSH;
  const long long offA = (long long)z * sA;
  const long long offB = (long long)(z >> bzsh) * sB;
  const long long offC = (long long)z * sC;
  const int row0 = blockIdx.x * 128;
  const int n0   = blockIdx.y * 128;
  const int lane = tid & 63;
  const int wv = tid >> 6;
  const int wm = wv >> 1, wn = wv & 1;
  const int fr = lane & 15, q = lane >> 4;
  const int srow = tid >> 2, skb = tid & 3;   // gload_lds: 4 lanes/row, 16B chunks

  f32x4 acc[4][4];
#pragma unroll
  for (int i=0;i<4;++i)
#pragma unroll
    for (int j=0;j<4;++j) acc[i][j] = (f32x4){0.f,0.f,0.f,0.f};

  const int ks0 = (SKIP == 2) ? (m >> 5) : 0;
  for (int ks = ks0; ks < ksteps; ++ks){
    const int k0 = ks * 32;
    // ---- stage A
    if (AMODE == 0){
      const int row = tid >> 1, half = tid & 1;
      const float* s = Af + offA + (long long)(row0 + row) * ldA + k0 + half*16;
      float vv[16];
      *(float4*)(vv+0)  = *(const float4*)(s+0);
      *(float4*)(vv+4)  = *(const float4*)(s+4);
      *(float4*)(vv+8)  = *(const float4*)(s+8);
      *(float4*)(vv+12) = *(const float4*)(s+12);
      ushort8 H0, H1;
#pragma unroll
      for (int j=0;j<8;++j){ H0[j] = f2bf(vv[j]); H1[j] = f2bf(vv[8+j]); }
      *(ushort8*)&As[row][half*16]   = H0;
      *(ushort8*)&As[row][half*16+8] = H1;
    } else {
#pragma unroll
      for (int i=0;i<2;++i){
        const unsigned short* g = Abf + offA + (long long)(row0 + i*64 + srow) * ldA + k0 + skb*8;
        gl_lds16(g, (unsigned short*)As + i*2048 + wv*512);
      }
    }
    // ---- stage B (always bf16, gload_lds)
#pragma unroll
    for (int i=0;i<2;++i){
      const unsigned short* g = Bt + offB + (long long)(n0 + i*64 + srow) * ldB + k0 + skb*8;
      gl_lds16(g, (unsigned short*)Bs + i*2048 + wv*512);
    }
    __syncthreads();   // compiler drains vmcnt(0) here: staged data visible
    bf16x8 ah[4];
#pragma unroll
    for (int mt=0;mt<4;++mt)
      ah[mt] = *(const bf16x8*)&As[wm*64 + mt*16 + fr][q*8];
#pragma unroll
    for (int nt=0;nt<4;++nt){
      bf16x8 bb = *(const bf16x8*)&Bs[wn*64 + nt*16 + fr][q*8];
#pragma unroll
      for (int mt=0;mt<4;++mt)
        acc[mt][nt] = __builtin_amdgcn_mfma_f32_16x16x32_bf16(ah[mt], bb, acc[mt][nt], 0,0,0);
    }
    __syncthreads();   // protect LDS before next stage
  }

  if (CMODE == 0){
#pragma unroll
    for (int mt=0;mt<4;++mt){
      int row = row0 + wm*64 + mt*16 + q*4;
      float bv0=0.f,bv1=0.f,bv2=0.f,bv3=0.f;
      if (BIAS){ bv0=bias[row]; bv1=bias[row+1]; bv2=bias[row+2]; bv3=bias[row+3]; }
#pragma unroll
      for (int nt=0;nt<4;++nt){
        int col = n0 + wn*64 + nt*16 + fr;
        float* dst = Cf + offC + (long long)row * ldC + col;
        dst[0]                = acc[mt][nt][0] + bv0;
        dst[(long long)ldC]   = acc[mt][nt][1] + bv1;
        dst[(long long)ldC*2] = acc[mt][nt][2] + bv2;
        dst[(long long)ldC*3] = acc[mt][nt][3] + bv3;
      }
    }
  } else if (CMODE == 1){
#pragma unroll
    for (int nt=0;nt<4;++nt){
      int colp = n0 + wn*64 + nt*16 + fr;
#pragma unroll
      for (int mt=0;mt<4;++mt){
        int rowb = row0 + wm*64 + mt*16 + q*4;
        ushort4v h;
        h[0] = f2bf(acc[mt][nt][0]);
        h[1] = f2bf(acc[mt][nt][1]);
        h[2] = f2bf(acc[mt][nt][2]);
        h[3] = f2bf(acc[mt][nt][3]);
        *(ushort4v*)&Cbf[offC + (long long)colp * ldC + rowb] = h;
      }
    }
  } else {
#pragma unroll
    for (int mt=0;mt<4;++mt){
      int row = row0 + wm*64 + mt*16 + q*4;
#pragma unroll
      for (int nt=0;nt<4;++nt){
        int col = n0 + wn*64 + nt*16 + fr;
        unsigned short* dst = Cbf + offC + (long long)row * ldC + col;
        dst[0]      = f2bf(acc[mt][nt][0]);
        dst[ldC]    = f2bf(acc[mt][nt][1]);
        dst[ldC*2]  = f2bf(acc[mt][nt][2]);
        dst[ldC*3]  = f2bf(acc[mt][nt][3]);
      }
    }
  }
}

// ------- transpose bf16 g[256 p][65536 r] -> gT[65536 r][256 p] ---------------
__global__ __launch_bounds__(256) void k_trb(const unsigned short* __restrict__ g,
                                             unsigned short* __restrict__ gT){
  __shared__ unsigned short t[64][68];
  const int r0 = blockIdx.x * 64;
  const int p0 = blockIdx.y * 64;
  const int tr = threadIdx.x & 15, tc = threadIdx.x >> 4;
#pragma unroll
  for (int i=0;i<4;++i){
    int pl = tc + i*16;
    ushort4v v = *(const ushort4v*)(g + (long long)(p0+pl)*ROWS_LO + r0 + tr*4);
    *(ushort4v*)&t[pl][tr*4] = v;
  }
  __syncthreads();
#pragma unroll
  for (int i=0;i<4;++i){
    int rl = tc + i*16;
    ushort4v w;
    w[0]=t[tr*4+0][rl]; w[1]=t[tr*4+1][rl]; w[2]=t[tr*4+2][rl]; w[3]=t[tr*4+3][rl];
    *(ushort4v*)(gT + (long long)(r0+rl)*256 + p0 + tr*4) = w;
  }
}

// ------- transpose y[b][256 c][32768 s] f32 -> yT[b][s][c] bf16 ---------------
__global__ __launch_bounds__(256) void k_tr2(const float* __restrict__ y,
                                             unsigned short* __restrict__ yT){
  __shared__ float t[64][65];
  const int s0 = blockIdx.x * 64;
  const int c0 = blockIdx.y * 64;
  const int b  = blockIdx.z;
  const int tr = threadIdx.x & 15, tc = threadIdx.x >> 4;
#pragma unroll
  for (int i=0;i<4;++i){
    int cl = tc + i*16;
    float4 v = *(const float4*)(y + (long long)b*8388608 + (long long)(c0+cl)*32768 + s0 + tr*4);
    t[cl][tr*4+0]=v.x; t[cl][tr*4+1]=v.y; t[cl][tr*4+2]=v.z; t[cl][tr*4+3]=v.w;
  }
  __syncthreads();
#pragma unroll
  for (int i=0;i<4;++i){
    int sl = tc + i*16;
    ushort4v w;
    w[0]=f2bf(t[tr*4+0][sl]); w[1]=f2bf(t[tr*4+1][sl]);
    w[2]=f2bf(t[tr*4+2][sl]); w[3]=f2bf(t[tr*4+3][sl]);
    *(ushort4v*)(yT + (long long)b*8388608 + (long long)(s0+sl)*256 + c0 + tr*4) = w;
  }
}

// ---------------- GroupNorm stats --------------------------------------------
__global__ __launch_bounds__(256) void k_stats(const float* __restrict__ h,
                                               float* __restrict__ stats){
  const int bg = blockIdx.y;
  const int j  = blockIdx.x;
  const int t  = threadIdx.x;
  const float* base = h + (long long)bg*262144 + j*8192;
  float s = 0.f, ss = 0.f;
#pragma unroll
  for (int i=0;i<8;++i){
    float4 v = *(const float4*)(base + i*1024 + t*4);
    s  += v.x + v.y + v.z + v.w;
    ss += v.x*v.x + v.y*v.y + v.z*v.z + v.w*v.w;
  }
#pragma unroll
  for (int off=32; off>0; off>>=1){
    s  += __shfl_down(s, off, 64);
    ss += __shfl_down(ss, off, 64);
  }
  __shared__ float red[8];
  int wid = t >> 6;
  if ((t & 63) == 0){ red[wid*2] = s; red[wid*2+1] = ss; }
  __syncthreads();
  if (t == 0){
    float S  = red[0]+red[2]+red[4]+red[6];
    float SS = red[1]+red[3]+red[5]+red[7];
    atomicAdd(&stats[bg*2+0], S);
    atomicAdd(&stats[bg*2+1], SS);
  }
}

// ---------------- normalize + affine + exact GELU ----------------------------
__global__ __launch_bounds__(256) void k_norm(float* __restrict__ out,
                                              const float* __restrict__ stats,
                                              const float* __restrict__ gamma,
                                              const float* __restrict__ beta){
  long long idx4 = ((long long)blockIdx.x*256 + threadIdx.x)*4;
  int o = (int)((idx4 >> 15) & 255);
  int b = (int)(idx4 >> 23);
  int bg = b*32 + (o >> 3);
  const float inv_n = 1.0f/262144.0f;
  float mean = stats[bg*2+0] * inv_n;
  float var  = stats[bg*2+1] * inv_n - mean*mean;
  float sc = rsqrtf(var + 1e-5f);
  float ga = gamma[o], be = beta[o];
  float4 v = *(float4*)(out + idx4);
  float t0 = (v.x - mean)*sc*ga + be;
  float t1 = (v.y - mean)*sc*ga + be;
  float t2 = (v.z - mean)*sc*ga + be;
  float t3 = (v.w - mean)*sc*ga + be;
  const float ISQ2 = 0.70710678118654752f;
  v.x = 0.5f*t0*(1.0f + erff(t0*ISQ2));
  v.y = 0.5f*t1*(1.0f + erff(t1*ISQ2));
  v.z = 0.5f*t2*(1.0f + erff(t2*ISQ2));
  v.w = 0.5f*t3*(1.0f + erff(t3*ISQ2));
  *(float4*)(out + idx4) = v;
}

extern "C" void kernel_launch(void* const* d_in, const int* in_sizes, int n_in,
                              void* d_out, int out_size, void* d_ws, size_t ws_size,
                              hipStream_t stream){
  const float* x      = (const float*)d_in[0];
  const float* conv_w = (const float*)d_in[1];
  const float* conv_b = (const float*)d_in[2];
  const float* gamma  = (const float*)d_in[3];
  const float* beta   = (const float*)d_in[4];
  const float* wmat   = (const float*)d_in[5];
  const float* pct    = (const float*)d_in[6];
  unsigned char* ws = (unsigned char*)d_ws;

  unsigned short* FT   = (unsigned short*)(ws + B_FT);
  unsigned short* FIT  = (unsigned short*)(ws + B_FIT);
  unsigned short* PT   = (unsigned short*)(ws + B_PCT);
  unsigned short* WB   = (unsigned short*)(ws + B_WB);
  unsigned short* WMT  = (unsigned short*)(ws + B_WMT);
  unsigned short* QM   = (unsigned short*)(ws + B_QM);
  float*          stats= (float*)(ws + B_STATS);
  unsigned short* Xbf  = (unsigned short*)(ws + B_XBF);
  unsigned short* gb   = (unsigned short*)(ws + B_GB);
  unsigned short* gTb  = (unsigned short*)(ws + B_GTB);
  float*          y    = (float*)(ws + B_Y);
  unsigned short* yT   = (unsigned short*)(ws + B_YT);
  float* out = (float*)d_out;

  k_tables<<<769, 256, 0, stream>>>(ws);
  k_prep  <<<41216, 256, 0, stream>>>(wmat, pct, conv_w, ws);

  // Q[m] = PT[m] * WM[m]^T : A=PT [128kp x 128l], Bt=WMT[m] [256k x 128l],
  // C=QM bf16 [128kp][256k]; k-loop starts at l>=m (SKIP2, m=z).
  k_gemm<1,2,false,2,0,3><<<dim3(1,2,128), 256, 0, stream>>>(
      nullptr, PT, WMT, nullptr, QM, nullptr, 128, 128, 256, 4,
      16384LL, 32768LL, 0, 32768LL);

  // DFT: A=x f32 [131072x512] (reg-staged quantize), B=F_T, C->Xbf trans bf16
  k_gemm<0,1,false,0,0,3><<<dim3(1024,2,1), 256, 0, stream>>>(
      x, nullptr, FT, nullptr, Xbf, nullptr, 512, 512, ROWS_HI, 16, 0, 0, 0, 0);

  // Fused leg: per plane p: A=Xbf[p] [512bc x 256k], Bt=QM[p>>1] [128kp x 256k],
  // C=gb bf16 [512bc][128kp]
  k_gemm<1,2,false,0,0,3><<<dim3(4,1,256), 256, 0, stream>>>(
      nullptr, Xbf, QM, nullptr, gb, nullptr, 256, 256, 128, 8,
      131072LL, 32768LL, 1, 65536LL);

  // transpose gb -> gTb
  k_trb<<<dim3(1024,4), 256, 0, stream>>>(gb, gTb);

  // iDFT: A=gTb [65536x256], B=Fi_T [256w'x256p], C=y f32
  k_gemm<1,0,false,0,0,3><<<dim3(512,2,1), 256, 0, stream>>>(
      nullptr, gTb, FIT, y, nullptr, nullptr, 256, 256, 256, 8, 0, 0, 0, 0);

  // transpose+quantize y -> yT bf16
  k_tr2<<<dim3(512,4,2), 256, 0, stream>>>(y, yT);

  // Conv: per b: A=WB [256o x 256c], B=yT[b] [32768s x 256c], C=out f32 +bias
  k_gemm<1,0,true,0,0,3><<<dim3(2,256,2), 256, 0, stream>>>(
      nullptr, WB, yT, out, nullptr, conv_b, 256, 256, 32768, 8,
      0, 8388608LL, 0, 8388608LL);

  k_stats<<<dim3(32,64), 256, 0, stream>>>(out, stats);
  k_norm <<<16384, 256, 0, stream>>>(out, stats, gamma, beta);
}